// Round 12
// baseline (122.454 us; speedup 1.0000x reference)
//
#include <hip/hip_runtime.h>
#include <cstdint>
#include <cstddef>

// ---------- types ----------
typedef __bf16 bf16;
typedef _Float16 f16;
typedef __attribute__((ext_vector_type(8))) __bf16 bf16x8;
typedef __attribute__((ext_vector_type(4))) float f32x4;
typedef __attribute__((ext_vector_type(16))) float f32x16;
typedef __attribute__((ext_vector_type(4))) _Float16 f16x4;
typedef __attribute__((ext_vector_type(8))) _Float16 f16x8;

#define MFMA16(a, b, c) __builtin_amdgcn_mfma_f32_16x16x32_bf16((a), (b), (c), 0, 0, 0)
#define MFMA32(a, b, c) __builtin_amdgcn_mfma_f32_32x32x16_bf16((a), (b), (c), 0, 0, 0)

// Problem constants (B=2, S=2048, HIDDEN=1024, H=16, D=64)
static constexpr int BB   = 2;
static constexpr int SS   = 2048;
static constexpr int HID  = 1024;
static constexpr int NH   = 16;
static constexpr int HD   = 64;
static constexpr int MROW = BB * SS;     // 4096
static constexpr int NQKV = 3 * HID;     // 3072
static constexpr float LOG2E = 1.4426950408889634f;
static constexpr float MSHIFT = 16.0f;   // static softmax shift (log2 domain)

// XOR swizzle on 16B slots
__device__ __forceinline__ int SW(int r) { return ((r ^ (r >> 3)) & 7) << 4; }

__device__ __forceinline__ uint32_t pack_bf16(float a, float b) {
    union { bf16 h[2]; uint32_t u; } x;
    x.h[0] = (bf16)a; x.h[1] = (bf16)b;
    return x.u;
}

__device__ __forceinline__ uint32_t pack_raw(bf16 a, bf16 b) {
    union { bf16 h[2]; uint32_t u; } x;
    x.h[0] = a; x.h[1] = b;
    return x.u;
}

__device__ __forceinline__ float exp2i(float x) {
    float r; asm("v_exp_f32 %0, %1" : "=v"(r) : "v"(x)); return r;
}

// v_permlane32_swap_b32: a' = [a.lo | b.lo], b' = [a.hi | b.hi]
__device__ __forceinline__ void plswap(uint32_t& a, uint32_t& b) {
    asm("v_permlane32_swap_b32 %0, %1" : "+v"(a), "+v"(b));
}

// async global->LDS, 16B per lane
__device__ __forceinline__ void gload16(const void* g, void* l) {
    __builtin_amdgcn_global_load_lds(
        (const __attribute__((address_space(1))) void*)g,
        (__attribute__((address_space(3))) void*)l, 16, 0, 0);
}

// ---------- kernel 1: fp32 -> bf16 convert ----------
__global__ __launch_bounds__(256) void cvt_hidden(const float* __restrict__ in,
                                                  bf16* __restrict__ out) {
    const int i = (blockIdx.x * 256 + threadIdx.x) * 8;
    float4 f0 = *(const float4*)&in[i];
    float4 f1 = *(const float4*)&in[i + 4];
    bf16x8 o;
    o[0] = (bf16)f0.x; o[1] = (bf16)f0.y; o[2] = (bf16)f0.z; o[3] = (bf16)f0.w;
    o[4] = (bf16)f1.x; o[5] = (bf16)f1.y; o[6] = (bf16)f1.z; o[7] = (bf16)f1.w;
    *(bf16x8*)&out[i] = o;
}

// ---------- kernel 1b: mask * log2e - MSHIFT ----------
__global__ __launch_bounds__(256) void maskcvt(const float* __restrict__ m,
                                               float* __restrict__ o) {
    const int i = blockIdx.x * 256 + threadIdx.x;
    o[i] = m[i] * LOG2E - MSHIFT;
}

// ---------- kernel 2: transpose-convert W -> Wt [n][k] bf16 ----------
__global__ __launch_bounds__(256) void wtrans(const float* __restrict__ Wq,
                                              const float* __restrict__ Wk,
                                              const float* __restrict__ Wv,
                                              bf16* __restrict__ Wt) {
    __shared__ float tile[32][33];
    const float* W = (blockIdx.z == 0) ? Wq : (blockIdx.z == 1) ? Wk : Wv;
    bf16* O = Wt + (size_t)blockIdx.z * HID * HID;
    const int x  = blockIdx.x * 32 + threadIdx.x;
    const int y0 = blockIdx.y * 32;
#pragma unroll
    for (int i = threadIdx.y; i < 32; i += 8)
        tile[i][threadIdx.x] = W[(size_t)(y0 + i) * HID + x];
    __syncthreads();
    const int k = y0 + threadIdx.x;
#pragma unroll
    for (int i = threadIdx.y; i < 32; i += 8)
        O[(size_t)(blockIdx.x * 32 + i) * HID + k] = (bf16)tile[threadIdx.x][i];
}

// ---------- kernel 3: QKV GEMM (global_load_lds staging; unchanged) ----------
__global__ __launch_bounds__(256) void qkv_gemm(
    const bf16* __restrict__ A, const bf16* __restrict__ Bt,
    const float* __restrict__ bq, const float* __restrict__ bk,
    const float* __restrict__ bv,
    bf16* __restrict__ Qo, bf16* __restrict__ Ko, bf16* __restrict__ Vo) {
    __shared__ __align__(16) bf16 As[128 * 32];
    __shared__ __align__(16) bf16 Bs[128 * 32];
    const int t = threadIdx.x, l = t & 63;
    const int l15 = l & 15, l4 = l >> 4;
    const int w = t >> 6;
    const int wm = w >> 1, wn = w & 1;
    const int m0 = blockIdx.y * 128, n0 = blockIdx.x * 128;

    f32x4 acc[4][4] = {};

    for (int kt = 0; kt < 32; ++kt) {
        const int k0 = kt * 32;
        __syncthreads();
#pragma unroll
        for (int cc = 0; cc < 2; ++cc) {
            const int c = t + cc * 256;
            const int row = c >> 2, col = (c & 3) * 8;
            gload16(&A[(size_t)(m0 + row) * HID + k0 + col], (char*)As + c * 16);
            gload16(&Bt[(size_t)(n0 + row) * HID + k0 + col], (char*)Bs + c * 16);
        }
        __syncthreads();

        bf16x8 af[4], bf_[4];
#pragma unroll
        for (int mi = 0; mi < 4; ++mi) {
            const int r = wm * 64 + mi * 16 + l15;
            af[mi] = *(const bf16x8*)((const char*)As + r * 64 + l4 * 16);
        }
#pragma unroll
        for (int ni = 0; ni < 4; ++ni) {
            const int r = wn * 64 + ni * 16 + l15;
            bf_[ni] = *(const bf16x8*)((const char*)Bs + r * 64 + l4 * 16);
        }
        __builtin_amdgcn_s_setprio(1);
#pragma unroll
        for (int mi = 0; mi < 4; ++mi)
#pragma unroll
            for (int ni = 0; ni < 4; ++ni)
                acc[mi][ni] = MFMA16(af[mi], bf_[ni], acc[mi][ni]);
        __builtin_amdgcn_s_setprio(0);
    }

#pragma unroll
    for (int mi = 0; mi < 4; ++mi) {
#pragma unroll
        for (int ni = 0; ni < 4; ++ni) {
            const int ng = n0 + wn * 64 + ni * 16 + l15;
            const int qkv = ng >> 10;
            const int nn = ng & 1023;
            const int hh = nn >> 6, dd = nn & 63;
            const float* bp = (qkv == 0) ? bq : (qkv == 1) ? bk : bv;
            bf16* op = (qkv == 0) ? Qo : (qkv == 1) ? Ko : Vo;
            const float bias = bp[nn];
            const float scl = (qkv == 0) ? 0.125f * LOG2E : 1.0f;
            const int mg = m0 + wm * 64 + mi * 16 + l4 * 4;
            const int bb = mg >> 11, ss = mg & 2047;
            bf16* dst = op + ((size_t)(bb * NH + hh) * SS + ss) * HD + dd;
#pragma unroll
            for (int j = 0; j < 4; ++j)
                dst[(size_t)j * HD] = (bf16)((acc[mi][ni][j] + bias) * scl);
        }
    }
}

// ---------- kernel 4: flash attention v12 — register diet ----------
// R10 base minus R9's "both-groups-QK-first": the two 32-key groups are now
// fully serialized (one 16-reg st instead of two), cutting ~16 live regs.
// Theory: true unified-file allocation was ~180/wave -> 2 waves/SIMD; this
// crosses back to 3 waves/SIMD (the R4-era 37% occupancy class).
__global__ __launch_bounds__(256) void attn_fwd(
    const bf16* __restrict__ Q, const bf16* __restrict__ K,
    const bf16* __restrict__ V, const float* __restrict__ mkl,
    f16* __restrict__ Op, float* __restrict__ ml) {
    __shared__ __align__(16) char Ks0[64 * 128];
    __shared__ __align__(16) char Ks1[64 * 128];
    __shared__ __align__(16) char Vt0[64 * 128];
    __shared__ __align__(16) char Vt1[64 * 128];

    const int t = threadIdx.x, l = t & 63, w = t >> 6;
    const int l31 = l & 31, h = l >> 5;

    const int bid = blockIdx.x;
    const int nid = (bid & 7) * 128 + (bid >> 3);   // 1024 = 8*128 bijective
    const int bh = nid >> 5, kh = (nid >> 4) & 1, qb = nid & 15;
    const int q0 = qb * 128 + w * 32;
    const int kbase = kh * (SS / 2);

    const bf16* Qp = Q + (size_t)bh * SS * HD;
    const bf16* Kp = K + (size_t)bh * SS * HD;
    const bf16* Vp = V + (size_t)bh * SS * HD;
    const float* mkp = mkl + (bh >> 4) * SS;

    // Q frags (B-operand): lane q = l31, d = c*16 + h*8 + e
    bf16x8 qf[4];
#pragma unroll
    for (int c = 0; c < 4; ++c)
        qf[c] = *(const bf16x8*)&Qp[(size_t)(q0 + l31) * HD + c * 16 + h * 8];

    float lrun = 0.f;
    f32x16 o0 = {}, o1 = {};   // O^T: rows d / d+32, col q = l31

    const int vp_ = t >> 3, vdb = (t & 7) * 8;

    // ---- staging helpers ----
    auto stageK = [&](int tile, char* dst) {
        const int key0 = kbase + tile * 64;
#pragma unroll
        for (int cc = 0; cc < 2; ++cc) {
            const int c = t + cc * 256;
            const int row = c >> 3;
            const int csw = (c & 7) ^ ((row ^ (row >> 3)) & 7);
            gload16(&Kp[(size_t)(key0 + row) * HD + csw * 8], dst + c * 16);
        }
    };
    auto loadV = [&](int tile, bf16x8& va, bf16x8& vb) {
        const int key0 = kbase + tile * 64;
        va = *(const bf16x8*)&Vp[(size_t)(key0 + 2 * vp_) * HD + vdb];
        vb = *(const bf16x8*)&Vp[(size_t)(key0 + 2 * vp_ + 1) * HD + vdb];
    };
    auto storeV = [&](char* Vtn, const bf16x8& va, const bf16x8& vb) {
#pragma unroll
        for (int i = 0; i < 8; ++i) {
            const int d = vdb + i;
            *(uint32_t*)(Vtn + d * 128 + ((vp_ * 4) ^ SW(d))) =
                pack_raw(va[i], vb[i]);
        }
    };

    // ---- prologue: stage tile 0 ----
    stageK(0, Ks0);
    {
        bf16x8 va, vb;
        loadV(0, va, vb);
        storeV(Vt0, va, vb);
    }
    __syncthreads();

    constexpr int NT = (SS / 2) / 64;   // 16
#pragma unroll 1
    for (int kt = 0; kt < NT; ++kt) {
        char* Ks = (kt & 1) ? Ks1 : Ks0;
        char* Vt = (kt & 1) ? Vt1 : Vt0;
        char* Ksn = (kt & 1) ? Ks0 : Ks1;
        char* Vtn = (kt & 1) ? Vt0 : Vt1;
        const int key0 = kbase + kt * 64;
        const bool more = (kt + 1) < NT;

        // ---- early-issue next tile staging ----
        bf16x8 va = {}, vb = {};
        if (more) {
            stageK(kt + 1, Ksn);
            loadV(kt + 1, va, vb);
        }

        // ---- per 32-key group: QK^T (C=mask') -> exp -> pack -> PV ----
#pragma unroll
        for (int g = 0; g < 2; ++g) {
            f32x16 st;
#pragma unroll
            for (int rq = 0; rq < 4; ++rq) {
                const f32x4 mv =
                    *(const f32x4*)&mkp[key0 + g * 32 + rq * 8 + 4 * h];
#pragma unroll
                for (int j = 0; j < 4; ++j) st[rq * 4 + j] = mv[j];
            }
            __builtin_amdgcn_s_setprio(1);
#pragma unroll
            for (int c = 0; c < 4; ++c) {
                const int r0 = g * 32 + l31;
                bf16x8 kf = *(const bf16x8*)(Ks + r0 * 128 +
                                             ((c * 32 + h * 16) ^ SW(r0)));
                st = MFMA32(kf, qf[c], st);
            }
            __builtin_amdgcn_s_setprio(0);

            float ps = 0.f;
#pragma unroll
            for (int r = 0; r < 16; ++r) {
                const float p = exp2i(st[r]);
                st[r] = p;
                ps += p;
            }
            lrun += ps;

#pragma unroll
            for (int cc = 0; cc < 2; ++cc) {
                uint32_t wA = pack_bf16(st[8 * cc + 0], st[8 * cc + 1]);
                uint32_t wB = pack_bf16(st[8 * cc + 2], st[8 * cc + 3]);
                uint32_t wC = pack_bf16(st[8 * cc + 4], st[8 * cc + 5]);
                uint32_t wD = pack_bf16(st[8 * cc + 6], st[8 * cc + 7]);
                plswap(wA, wC);
                plswap(wB, wD);
                union { uint32_t u[4]; bf16x8 v; } pb;
                pb.u[0] = wA; pb.u[1] = wB; pb.u[2] = wC; pb.u[3] = wD;
                const int colb = g * 64 + cc * 32 + h * 16;
                __builtin_amdgcn_s_setprio(1);
                {
                    bf16x8 vf0 = *(const bf16x8*)(Vt + l31 * 128 +
                                                  (colb ^ SW(l31)));
                    o0 = MFMA32(vf0, pb.v, o0);
                    const int r1 = 32 + l31;
                    bf16x8 vf1 = *(const bf16x8*)(Vt + r1 * 128 +
                                                  (colb ^ SW(r1)));
                    o1 = MFMA32(vf1, pb.v, o1);
                }
                __builtin_amdgcn_s_setprio(0);
            }
            // write next V tile mid-compute (after g0's PV; frees va/vb)
            if (g == 0 && more) storeV(Vtn, va, vb);
        }
        __syncthreads();   // single barrier per tile
    }

    // ---- epilogue: f16 partials + l ----
    lrun += __shfl_xor(lrun, 32);
    const int part = kh * 512 + bh * 16 + qb;
    f16* Ob = Op + (size_t)part * 8192;
    const int row = w * 32 + l31;
#pragma unroll
    for (int rq = 0; rq < 4; ++rq) {
        f16x4 a, b2;
#pragma unroll
        for (int j = 0; j < 4; ++j) {
            a[j]  = (f16)o0[rq * 4 + j];
            b2[j] = (f16)o1[rq * 4 + j];
        }
        *(f16x4*)&Ob[row * 64 + rq * 8 + 4 * h] = a;
        *(f16x4*)&Ob[row * 64 + 32 + rq * 8 + 4 * h] = b2;
    }
    if (l < 32) ml[(size_t)part * 128 + (w * 32 + l)] = lrun;
}

// ---------- kernel 5: split-K combine (2 partials, f16, 8-d per thread) ----------
__global__ __launch_bounds__(256) void combine(
    const f16* __restrict__ Op, const float* __restrict__ ml,
    float* __restrict__ out) {
    const int tid = blockIdx.x * 256 + threadIdx.x;
    const int dg = tid & 7, gq = tid >> 3;
    const int bh = gq >> 11, s = gq & 2047;
    const int qb = s >> 7, q = s & 127;
    const int p0 = bh * 16 + qb, p1 = 512 + p0;

    const float l1 = ml[(size_t)p0 * 128 + q];
    const float l2 = ml[(size_t)p1 * 128 + q];
    const float inv = 1.0f / (l1 + l2);

    const f16x8 O1 = *(const f16x8*)&Op[(size_t)p0 * 8192 + q * 64 + dg * 8];
    const f16x8 O2 = *(const f16x8*)&Op[(size_t)p1 * 8192 + q * 64 + dg * 8];
    f32x4 r0, r1;
#pragma unroll
    for (int i = 0; i < 4; ++i) {
        r0[i] = ((float)O1[i] + (float)O2[i]) * inv;
        r1[i] = ((float)O1[4 + i] + (float)O2[4 + i]) * inv;
    }

    const int b = bh >> 4, hh = bh & 15;
    float* op = &out[((size_t)(b * SS + s)) * HID + hh * HD + dg * 8];
    *(f32x4*)op = r0;
    *(f32x4*)(op + 4) = r1;
}

// ---------- launch ----------
extern "C" void kernel_launch(void* const* d_in, const int* in_sizes, int n_in,
                              void* d_out, int out_size, void* d_ws, size_t ws_size,
                              hipStream_t stream) {
    (void)in_sizes; (void)n_in; (void)out_size; (void)ws_size;
    const float* hs  = (const float*)d_in[0];
    const float* msk = (const float*)d_in[1];
    const float* Wq  = (const float*)d_in[2];
    const float* bq  = (const float*)d_in[3];
    const float* Wk  = (const float*)d_in[4];
    const float* bk  = (const float*)d_in[5];
    const float* Wv  = (const float*)d_in[6];
    const float* bv  = (const float*)d_in[7];
    float* out = (float*)d_out;
    char* ws = (char*)d_ws;
    const size_t MB = 1 << 20;

    bf16* Qb  = (bf16*)ws;                    // 0..8MB   [B,H,S,D]
    bf16* Kb  = (bf16*)(ws + 8 * MB);         // 8..16
    bf16* Vb  = (bf16*)(ws + 16 * MB);        // 16..24
    float* mk2 = (float*)(ws + 24 * MB);      // 24MB + 16KB
    bf16* Xb  = (bf16*)(ws + 25 * MB);        // 25..33 (dead after gemm)
    bf16* Wt  = (bf16*)(ws + 33 * MB);        // 33..39 (dead after gemm)
    f16* Opp  = (f16*)(ws + 25 * MB);         // 25..41 (aliases Xb/Wt, 16MB)
    float* mlp = (float*)(ws + 59 * MB);      // 59..60

    cvt_hidden<<<dim3(MROW * HID / (256 * 8)), dim3(256), 0, stream>>>(hs, Xb);
    maskcvt<<<dim3(BB * SS / 256), dim3(256), 0, stream>>>(msk, mk2);
    wtrans<<<dim3(32, 32, 3), dim3(32, 8), 0, stream>>>(Wq, Wk, Wv, Wt);
    qkv_gemm<<<dim3(NQKV / 128, MROW / 128), dim3(256), 0, stream>>>(
        Xb, Wt, bq, bk, bv, Qb, Kb, Vb);
    attn_fwd<<<dim3(1024), dim3(256), 0, stream>>>(Qb, Kb, Vb, mk2, Opp, mlp);
    combine<<<dim3(2048), dim3(256), 0, stream>>>(Opp, mlp, out);
}

// Round 13
// 119.640 us; speedup vs baseline: 1.0235x; 1.0235x over previous
//
#include <hip/hip_runtime.h>
#include <cstdint>
#include <cstddef>

// ---------- types ----------
typedef __bf16 bf16;
typedef _Float16 f16;
typedef __attribute__((ext_vector_type(8))) __bf16 bf16x8;
typedef __attribute__((ext_vector_type(4))) float f32x4;
typedef __attribute__((ext_vector_type(16))) float f32x16;
typedef __attribute__((ext_vector_type(4))) _Float16 f16x4;
typedef __attribute__((ext_vector_type(8))) _Float16 f16x8;
typedef __attribute__((ext_vector_type(4))) short short4v;

#define MFMA16(a, b, c) __builtin_amdgcn_mfma_f32_16x16x32_bf16((a), (b), (c), 0, 0, 0)
#define MFMA32(a, b, c) __builtin_amdgcn_mfma_f32_32x32x16_bf16((a), (b), (c), 0, 0, 0)

// Problem constants (B=2, S=2048, HIDDEN=1024, H=16, D=64)
static constexpr int BB   = 2;
static constexpr int SS   = 2048;
static constexpr int HID  = 1024;
static constexpr int NH   = 16;
static constexpr int HD   = 64;
static constexpr int MROW = BB * SS;     // 4096
static constexpr int NQKV = 3 * HID;     // 3072
static constexpr float LOG2E = 1.4426950408889634f;
static constexpr float MSHIFT = 16.0f;   // static softmax shift (log2 domain)

// XOR swizzle on 16B slots
__device__ __forceinline__ int SW(int r) { return ((r ^ (r >> 3)) & 7) << 4; }

__device__ __forceinline__ uint32_t pack_bf16(float a, float b) {
    union { bf16 h[2]; uint32_t u; } x;
    x.h[0] = (bf16)a; x.h[1] = (bf16)b;
    return x.u;
}

__device__ __forceinline__ float exp2i(float x) {
    float r; asm("v_exp_f32 %0, %1" : "=v"(r) : "v"(x)); return r;
}

// v_permlane32_swap_b32: a' = [a.lo | b.lo], b' = [a.hi | b.hi]
__device__ __forceinline__ void plswap(uint32_t& a, uint32_t& b) {
    asm("v_permlane32_swap_b32 %0, %1" : "+v"(a), "+v"(b));
}

// async global->LDS, 16B per lane
__device__ __forceinline__ void gload16(const void* g, void* l) {
    __builtin_amdgcn_global_load_lds(
        (const __attribute__((address_space(1))) void*)g,
        (__attribute__((address_space(3))) void*)l, 16, 0, 0);
}

// ---------- kernel 1: fp32 -> bf16 convert ----------
__global__ __launch_bounds__(256) void cvt_hidden(const float* __restrict__ in,
                                                  bf16* __restrict__ out) {
    const int i = (blockIdx.x * 256 + threadIdx.x) * 8;
    float4 f0 = *(const float4*)&in[i];
    float4 f1 = *(const float4*)&in[i + 4];
    bf16x8 o;
    o[0] = (bf16)f0.x; o[1] = (bf16)f0.y; o[2] = (bf16)f0.z; o[3] = (bf16)f0.w;
    o[4] = (bf16)f1.x; o[5] = (bf16)f1.y; o[6] = (bf16)f1.z; o[7] = (bf16)f1.w;
    *(bf16x8*)&out[i] = o;
}

// ---------- kernel 1b: mask * log2e - MSHIFT ----------
__global__ __launch_bounds__(256) void maskcvt(const float* __restrict__ m,
                                               float* __restrict__ o) {
    const int i = blockIdx.x * 256 + threadIdx.x;
    o[i] = m[i] * LOG2E - MSHIFT;
}

// ---------- kernel 2: transpose-convert W -> Wt [n][k] bf16 ----------
__global__ __launch_bounds__(256) void wtrans(const float* __restrict__ Wq,
                                              const float* __restrict__ Wk,
                                              const float* __restrict__ Wv,
                                              bf16* __restrict__ Wt) {
    __shared__ float tile[32][33];
    const float* W = (blockIdx.z == 0) ? Wq : (blockIdx.z == 1) ? Wk : Wv;
    bf16* O = Wt + (size_t)blockIdx.z * HID * HID;
    const int x  = blockIdx.x * 32 + threadIdx.x;
    const int y0 = blockIdx.y * 32;
#pragma unroll
    for (int i = threadIdx.y; i < 32; i += 8)
        tile[i][threadIdx.x] = W[(size_t)(y0 + i) * HID + x];
    __syncthreads();
    const int k = y0 + threadIdx.x;
#pragma unroll
    for (int i = threadIdx.y; i < 32; i += 8)
        O[(size_t)(blockIdx.x * 32 + i) * HID + k] = (bf16)tile[threadIdx.x][i];
}

// ---------- kernel 3: QKV GEMM ----------
// Q,K written [B,H,S,D]; V written PRE-TRANSPOSED [B*H][D][S] so attention
// can stage V^T via global_load_lds (V-third epilogue: one 8B store per frag).
__global__ __launch_bounds__(256) void qkv_gemm(
    const bf16* __restrict__ A, const bf16* __restrict__ Bt,
    const float* __restrict__ bq, const float* __restrict__ bk,
    const float* __restrict__ bv,
    bf16* __restrict__ Qo, bf16* __restrict__ Ko, bf16* __restrict__ Vo) {
    __shared__ __align__(16) bf16 As[128 * 32];
    __shared__ __align__(16) bf16 Bs[128 * 32];
    const int t = threadIdx.x, l = t & 63;
    const int l15 = l & 15, l4 = l >> 4;
    const int w = t >> 6;
    const int wm = w >> 1, wn = w & 1;
    const int m0 = blockIdx.y * 128, n0 = blockIdx.x * 128;

    f32x4 acc[4][4] = {};

    for (int kt = 0; kt < 32; ++kt) {
        const int k0 = kt * 32;
        __syncthreads();
#pragma unroll
        for (int cc = 0; cc < 2; ++cc) {
            const int c = t + cc * 256;
            const int row = c >> 2, col = (c & 3) * 8;
            gload16(&A[(size_t)(m0 + row) * HID + k0 + col], (char*)As + c * 16);
            gload16(&Bt[(size_t)(n0 + row) * HID + k0 + col], (char*)Bs + c * 16);
        }
        __syncthreads();

        bf16x8 af[4], bf_[4];
#pragma unroll
        for (int mi = 0; mi < 4; ++mi) {
            const int r = wm * 64 + mi * 16 + l15;
            af[mi] = *(const bf16x8*)((const char*)As + r * 64 + l4 * 16);
        }
#pragma unroll
        for (int ni = 0; ni < 4; ++ni) {
            const int r = wn * 64 + ni * 16 + l15;
            bf_[ni] = *(const bf16x8*)((const char*)Bs + r * 64 + l4 * 16);
        }
        __builtin_amdgcn_s_setprio(1);
#pragma unroll
        for (int mi = 0; mi < 4; ++mi)
#pragma unroll
            for (int ni = 0; ni < 4; ++ni)
                acc[mi][ni] = MFMA16(af[mi], bf_[ni], acc[mi][ni]);
        __builtin_amdgcn_s_setprio(0);
    }

#pragma unroll
    for (int mi = 0; mi < 4; ++mi) {
#pragma unroll
        for (int ni = 0; ni < 4; ++ni) {
            const int ng = n0 + wn * 64 + ni * 16 + l15;
            const int qkv = ng >> 10;       // uniform across 16-lane group
            const int nn = ng & 1023;
            const int hh = nn >> 6, dd = nn & 63;
            const int mg = m0 + wm * 64 + mi * 16 + l4 * 4;
            const int bb = mg >> 11, ss = mg & 2047;
            if (qkv == 2) {
                // V^T [BH][D][S]: 4 consecutive s at fixed d -> one 8B store
                const float bias = bv[nn];
                union { bf16 h[4]; short4v s4; } pk_;
#pragma unroll
                for (int j = 0; j < 4; ++j)
                    pk_.h[j] = (bf16)(acc[mi][ni][j] + bias);
                bf16* dst = Vo + ((size_t)(bb * NH + hh) * HD + dd) * SS + ss;
                *(short4v*)dst = pk_.s4;    // ss % 4 == 0 -> 8B aligned
            } else {
                const float* bp = (qkv == 0) ? bq : bk;
                bf16* op = (qkv == 0) ? Qo : Ko;
                const float bias = bp[nn];
                const float scl = (qkv == 0) ? 0.125f * LOG2E : 1.0f;
                bf16* dst = op + ((size_t)(bb * NH + hh) * SS + ss) * HD + dd;
#pragma unroll
                for (int j = 0; j < 4; ++j)
                    dst[(size_t)j * HD] = (bf16)((acc[mi][ni][j] + bias) * scl);
            }
        }
    }
}

// ---------- kernel 4: flash attention v13 ----------
// R10 base (best measured) minus ones-MFMA, with V^T staged via
// global_load_lds from the pre-transposed [BH][D][S] buffer (same
// pre-swizzled-source involution as K). Deletes loadV/storeV (2 VMEM +
// 8 LDS writes + 16 live regs per thread/tile). 2-way split-K.
__global__ __launch_bounds__(256) void attn_fwd(
    const bf16* __restrict__ Q, const bf16* __restrict__ K,
    const bf16* __restrict__ Vt_g, const float* __restrict__ mkl,
    f16* __restrict__ Op, float* __restrict__ ml) {
    __shared__ __align__(16) char Ks0[64 * 128];
    __shared__ __align__(16) char Ks1[64 * 128];
    __shared__ __align__(16) char Vt0[64 * 128];
    __shared__ __align__(16) char Vt1[64 * 128];

    const int t = threadIdx.x, l = t & 63, w = t >> 6;
    const int l31 = l & 31, h = l >> 5;

    const int bid = blockIdx.x;
    const int nid = (bid & 7) * 128 + (bid >> 3);   // 1024 = 8*128 bijective
    const int bh = nid >> 5, kh = (nid >> 4) & 1, qb = nid & 15;
    const int q0 = qb * 128 + w * 32;
    const int kbase = kh * (SS / 2);

    const bf16* Qp  = Q + (size_t)bh * SS * HD;
    const bf16* Kp  = K + (size_t)bh * SS * HD;
    const bf16* Vpt = Vt_g + (size_t)bh * HD * SS;   // [D][S]
    const float* mkp = mkl + (bh >> 4) * SS;

    // Q frags (B-operand): lane q = l31, d = c*16 + h*8 + e
    bf16x8 qf[4];
#pragma unroll
    for (int c = 0; c < 4; ++c)
        qf[c] = *(const bf16x8*)&Qp[(size_t)(q0 + l31) * HD + c * 16 + h * 8];

    float lrun = 0.f;
    f32x16 o0 = {}, o1 = {};   // O^T: rows d / d+32, col q = l31

    // ---- staging helpers (both K and V^T via global_load_lds) ----
    auto stageK = [&](int tile, char* dst) {
        const int key0 = kbase + tile * 64;
#pragma unroll
        for (int cc = 0; cc < 2; ++cc) {
            const int c = t + cc * 256;
            const int row = c >> 3;                  // key
            const int csw = (c & 7) ^ ((row ^ (row >> 3)) & 7);
            gload16(&Kp[(size_t)(key0 + row) * HD + csw * 8], dst + c * 16);
        }
    };
    auto stageVt = [&](int tile, char* dst) {
        const int key0 = kbase + tile * 64;
#pragma unroll
        for (int cc = 0; cc < 2; ++cc) {
            const int c = t + cc * 256;
            const int row = c >> 3;                  // d
            const int csw = (c & 7) ^ ((row ^ (row >> 3)) & 7);
            gload16(&Vpt[(size_t)row * SS + key0 + csw * 8], dst + c * 16);
        }
    };

    // ---- prologue: stage tile 0 ----
    stageK(0, Ks0);
    stageVt(0, Vt0);
    __syncthreads();

    constexpr int NT = (SS / 2) / 64;   // 16
#pragma unroll 1
    for (int kt = 0; kt < NT; ++kt) {
        char* Ks = (kt & 1) ? Ks1 : Ks0;
        char* Vt = (kt & 1) ? Vt1 : Vt0;
        char* Ksn = (kt & 1) ? Ks0 : Ks1;
        char* Vtn = (kt & 1) ? Vt0 : Vt1;
        const int key0 = kbase + kt * 64;
        const bool more = (kt + 1) < NT;

        // ---- early-issue next tile staging (async DMA, other buffers) ----
        if (more) {
            stageK(kt + 1, Ksn);
            stageVt(kt + 1, Vtn);
        }

        // ---- QK^T both groups; C-operand = mask' (log2-domain additive) ----
        f32x16 s0, s1;
#pragma unroll
        for (int rq = 0; rq < 4; ++rq) {
            const f32x4 m0v = *(const f32x4*)&mkp[key0 + rq * 8 + 4 * h];
            const f32x4 m1v = *(const f32x4*)&mkp[key0 + 32 + rq * 8 + 4 * h];
#pragma unroll
            for (int j = 0; j < 4; ++j) {
                s0[rq * 4 + j] = m0v[j];
                s1[rq * 4 + j] = m1v[j];
            }
        }
        __builtin_amdgcn_s_setprio(1);
#pragma unroll
        for (int c = 0; c < 4; ++c) {
            const int r0 = l31;
            bf16x8 kf0 = *(const bf16x8*)(Ks + r0 * 128 +
                                          ((c * 32 + h * 16) ^ SW(r0)));
            s0 = MFMA32(kf0, qf[c], s0);
        }
#pragma unroll
        for (int c = 0; c < 4; ++c) {
            const int r1 = 32 + l31;
            bf16x8 kf1 = *(const bf16x8*)(Ks + r1 * 128 +
                                          ((c * 32 + h * 16) ^ SW(r1)));
            s1 = MFMA32(kf1, qf[c], s1);
        }
        __builtin_amdgcn_s_setprio(0);

        // ---- softmax + PV per group (static shift; p = 2^s) ----
#pragma unroll
        for (int g = 0; g < 2; ++g) {
            f32x16& st = g ? s1 : s0;
            float ps = 0.f;
#pragma unroll
            for (int r = 0; r < 16; ++r) {
                const float p = exp2i(st[r]);
                st[r] = p;
                ps += p;
            }
            lrun += ps;
#pragma unroll
            for (int cc = 0; cc < 2; ++cc) {
                uint32_t wA = pack_bf16(st[8 * cc + 0], st[8 * cc + 1]);
                uint32_t wB = pack_bf16(st[8 * cc + 2], st[8 * cc + 3]);
                uint32_t wC = pack_bf16(st[8 * cc + 4], st[8 * cc + 5]);
                uint32_t wD = pack_bf16(st[8 * cc + 6], st[8 * cc + 7]);
                plswap(wA, wC);
                plswap(wB, wD);
                union { uint32_t u[4]; bf16x8 v; } pb;
                pb.u[0] = wA; pb.u[1] = wB; pb.u[2] = wC; pb.u[3] = wD;
                const int colb = g * 64 + cc * 32 + h * 16;
                __builtin_amdgcn_s_setprio(1);
                {
                    bf16x8 vf0 = *(const bf16x8*)(Vt + l31 * 128 +
                                                  (colb ^ SW(l31)));
                    o0 = MFMA32(vf0, pb.v, o0);
                    const int r1 = 32 + l31;
                    bf16x8 vf1 = *(const bf16x8*)(Vt + r1 * 128 +
                                                  (colb ^ SW(r1)));
                    o1 = MFMA32(vf1, pb.v, o1);
                }
                __builtin_amdgcn_s_setprio(0);
            }
        }
        __syncthreads();   // single barrier per tile (drains next-tile DMA)
    }

    // ---- epilogue: f16 partials + l ----
    lrun += __shfl_xor(lrun, 32);
    const int part = kh * 512 + bh * 16 + qb;
    f16* Ob = Op + (size_t)part * 8192;
    const int row = w * 32 + l31;
#pragma unroll
    for (int rq = 0; rq < 4; ++rq) {
        f16x4 a, b2;
#pragma unroll
        for (int j = 0; j < 4; ++j) {
            a[j]  = (f16)o0[rq * 4 + j];
            b2[j] = (f16)o1[rq * 4 + j];
        }
        *(f16x4*)&Ob[row * 64 + rq * 8 + 4 * h] = a;
        *(f16x4*)&Ob[row * 64 + 32 + rq * 8 + 4 * h] = b2;
    }
    if (l < 32) ml[(size_t)part * 128 + (w * 32 + l)] = lrun;
}

// ---------- kernel 5: split-K combine (2 partials, f16, 8-d per thread) ----------
__global__ __launch_bounds__(256) void combine(
    const f16* __restrict__ Op, const float* __restrict__ ml,
    float* __restrict__ out) {
    const int tid = blockIdx.x * 256 + threadIdx.x;
    const int dg = tid & 7, gq = tid >> 3;
    const int bh = gq >> 11, s = gq & 2047;
    const int qb = s >> 7, q = s & 127;
    const int p0 = bh * 16 + qb, p1 = 512 + p0;

    const float l1 = ml[(size_t)p0 * 128 + q];
    const float l2 = ml[(size_t)p1 * 128 + q];
    const float inv = 1.0f / (l1 + l2);

    const f16x8 O1 = *(const f16x8*)&Op[(size_t)p0 * 8192 + q * 64 + dg * 8];
    const f16x8 O2 = *(const f16x8*)&Op[(size_t)p1 * 8192 + q * 64 + dg * 8];
    f32x4 r0, r1;
#pragma unroll
    for (int i = 0; i < 4; ++i) {
        r0[i] = ((float)O1[i] + (float)O2[i]) * inv;
        r1[i] = ((float)O1[4 + i] + (float)O2[4 + i]) * inv;
    }

    const int b = bh >> 4, hh = bh & 15;
    float* op = &out[((size_t)(b * SS + s)) * HID + hh * HD + dg * 8];
    *(f32x4*)op = r0;
    *(f32x4*)(op + 4) = r1;
}

// ---------- launch ----------
extern "C" void kernel_launch(void* const* d_in, const int* in_sizes, int n_in,
                              void* d_out, int out_size, void* d_ws, size_t ws_size,
                              hipStream_t stream) {
    (void)in_sizes; (void)n_in; (void)out_size; (void)ws_size;
    const float* hs  = (const float*)d_in[0];
    const float* msk = (const float*)d_in[1];
    const float* Wq  = (const float*)d_in[2];
    const float* bq  = (const float*)d_in[3];
    const float* Wk  = (const float*)d_in[4];
    const float* bk  = (const float*)d_in[5];
    const float* Wv  = (const float*)d_in[6];
    const float* bv  = (const float*)d_in[7];
    float* out = (float*)d_out;
    char* ws = (char*)d_ws;
    const size_t MB = 1 << 20;

    bf16* Qb  = (bf16*)ws;                    // 0..8MB   [B,H,S,D]
    bf16* Kb  = (bf16*)(ws + 8 * MB);         // 8..16    [B,H,S,D]
    bf16* Vb  = (bf16*)(ws + 16 * MB);        // 16..24   [BH][D][S] (transposed)
    float* mk2 = (float*)(ws + 24 * MB);      // 24MB + 16KB
    bf16* Xb  = (bf16*)(ws + 25 * MB);        // 25..33 (dead after gemm)
    bf16* Wt  = (bf16*)(ws + 33 * MB);        // 33..39 (dead after gemm)
    f16* Opp  = (f16*)(ws + 25 * MB);         // 25..41 (aliases Xb/Wt, 16MB)
    float* mlp = (float*)(ws + 59 * MB);      // 59..60

    cvt_hidden<<<dim3(MROW * HID / (256 * 8)), dim3(256), 0, stream>>>(hs, Xb);
    maskcvt<<<dim3(BB * SS / 256), dim3(256), 0, stream>>>(msk, mk2);
    wtrans<<<dim3(32, 32, 3), dim3(32, 8), 0, stream>>>(Wq, Wk, Wv, Wt);
    qkv_gemm<<<dim3(NQKV / 128, MROW / 128), dim3(256), 0, stream>>>(
        Xb, Wt, bq, bk, bv, Qb, Kb, Vb);
    attn_fwd<<<dim3(1024), dim3(256), 0, stream>>>(Qb, Kb, Vb, mk2, Opp, mlp);
    combine<<<dim3(2048), dim3(256), 0, stream>>>(Opp, mlp, out);
}

// Round 14
// 114.681 us; speedup vs baseline: 1.0678x; 1.0432x over previous
//
#include <hip/hip_runtime.h>
#include <cstdint>
#include <cstddef>

// ---------- types ----------
typedef __bf16 bf16;
typedef __attribute__((ext_vector_type(8))) __bf16 bf16x8;
typedef __attribute__((ext_vector_type(4))) float f32x4;
typedef __attribute__((ext_vector_type(16))) float f32x16;
typedef __attribute__((ext_vector_type(4))) short short4v;

#define MFMA16(a, b, c) __builtin_amdgcn_mfma_f32_16x16x32_bf16((a), (b), (c), 0, 0, 0)
#define MFMA32(a, b, c) __builtin_amdgcn_mfma_f32_32x32x16_bf16((a), (b), (c), 0, 0, 0)

// Problem constants (B=2, S=2048, HIDDEN=1024, H=16, D=64)
static constexpr int BB   = 2;
static constexpr int SS   = 2048;
static constexpr int HID  = 1024;
static constexpr int NH   = 16;
static constexpr int HD   = 64;
static constexpr int MROW = BB * SS;     // 4096
static constexpr int NQKV = 3 * HID;     // 3072
static constexpr float LOG2E = 1.4426950408889634f;
static constexpr float MSHIFT = 16.0f;   // static softmax shift (log2 domain)

// XOR swizzle on 16B slots
__device__ __forceinline__ int SW(int r) { return ((r ^ (r >> 3)) & 7) << 4; }

__device__ __forceinline__ uint32_t pack_bf16(float a, float b) {
    union { bf16 h[2]; uint32_t u; } x;
    x.h[0] = (bf16)a; x.h[1] = (bf16)b;
    return x.u;
}

__device__ __forceinline__ float exp2i(float x) {
    float r; asm("v_exp_f32 %0, %1" : "=v"(r) : "v"(x)); return r;
}

// v_permlane32_swap_b32: a' = [a.lo | b.lo], b' = [a.hi | b.hi]
__device__ __forceinline__ void plswap(uint32_t& a, uint32_t& b) {
    asm("v_permlane32_swap_b32 %0, %1" : "+v"(a), "+v"(b));
}

// async global->LDS, 16B per lane
__device__ __forceinline__ void gload16(const void* g, void* l) {
    __builtin_amdgcn_global_load_lds(
        (const __attribute__((address_space(1))) void*)g,
        (__attribute__((address_space(3))) void*)l, 16, 0, 0);
}

// ---------- kernel 1: fp32 -> bf16 convert ----------
__global__ __launch_bounds__(256) void cvt_hidden(const float* __restrict__ in,
                                                  bf16* __restrict__ out) {
    const int i = (blockIdx.x * 256 + threadIdx.x) * 8;
    float4 f0 = *(const float4*)&in[i];
    float4 f1 = *(const float4*)&in[i + 4];
    bf16x8 o;
    o[0] = (bf16)f0.x; o[1] = (bf16)f0.y; o[2] = (bf16)f0.z; o[3] = (bf16)f0.w;
    o[4] = (bf16)f1.x; o[5] = (bf16)f1.y; o[6] = (bf16)f1.z; o[7] = (bf16)f1.w;
    *(bf16x8*)&out[i] = o;
}

// ---------- kernel 1b: mask * log2e - MSHIFT ----------
__global__ __launch_bounds__(256) void maskcvt(const float* __restrict__ m,
                                               float* __restrict__ o) {
    const int i = blockIdx.x * 256 + threadIdx.x;
    o[i] = m[i] * LOG2E - MSHIFT;
}

// ---------- kernel 2: transpose-convert W -> Wt [n][k] bf16 ----------
__global__ __launch_bounds__(256) void wtrans(const float* __restrict__ Wq,
                                              const float* __restrict__ Wk,
                                              const float* __restrict__ Wv,
                                              bf16* __restrict__ Wt) {
    __shared__ float tile[32][33];
    const float* W = (blockIdx.z == 0) ? Wq : (blockIdx.z == 1) ? Wk : Wv;
    bf16* O = Wt + (size_t)blockIdx.z * HID * HID;
    const int x  = blockIdx.x * 32 + threadIdx.x;
    const int y0 = blockIdx.y * 32;
#pragma unroll
    for (int i = threadIdx.y; i < 32; i += 8)
        tile[i][threadIdx.x] = W[(size_t)(y0 + i) * HID + x];
    __syncthreads();
    const int k = y0 + threadIdx.x;
#pragma unroll
    for (int i = threadIdx.y; i < 32; i += 8)
        O[(size_t)(blockIdx.x * 32 + i) * HID + k] = (bf16)tile[threadIdx.x][i];
}

// ---------- kernel 3: QKV GEMM (1D grid + XCD col-major remap) ----------
// Q,K written [B,H,S,D]; V written PRE-TRANSPOSED [B*H][D][S].
// XCD remap: 768 = 8*96; each XCD owns 3 n-columns x 32 m-rows so its
// Wt panel (3*128*1024*2B = 768KB) stays L2-resident.
__global__ __launch_bounds__(256) void qkv_gemm(
    const bf16* __restrict__ A, const bf16* __restrict__ Bt,
    const float* __restrict__ bq, const float* __restrict__ bk,
    const float* __restrict__ bv,
    bf16* __restrict__ Qo, bf16* __restrict__ Ko, bf16* __restrict__ Vo) {
    __shared__ __align__(16) bf16 As[128 * 32];
    __shared__ __align__(16) bf16 Bs[128 * 32];
    const int t = threadIdx.x, l = t & 63;
    const int l15 = l & 15, l4 = l >> 4;
    const int w = t >> 6;
    const int wm = w >> 1, wn = w & 1;

    const int bid = blockIdx.x;
    const int nid = (bid & 7) * 96 + (bid >> 3);   // bijective: 768 = 8*96
    const int m0 = (nid & 31) * 128;
    const int n0 = (nid >> 5) * 128;

    f32x4 acc[4][4] = {};

    for (int kt = 0; kt < 32; ++kt) {
        const int k0 = kt * 32;
        __syncthreads();
#pragma unroll
        for (int cc = 0; cc < 2; ++cc) {
            const int c = t + cc * 256;
            const int row = c >> 2, col = (c & 3) * 8;
            gload16(&A[(size_t)(m0 + row) * HID + k0 + col], (char*)As + c * 16);
            gload16(&Bt[(size_t)(n0 + row) * HID + k0 + col], (char*)Bs + c * 16);
        }
        __syncthreads();

        bf16x8 af[4], bf_[4];
#pragma unroll
        for (int mi = 0; mi < 4; ++mi) {
            const int r = wm * 64 + mi * 16 + l15;
            af[mi] = *(const bf16x8*)((const char*)As + r * 64 + l4 * 16);
        }
#pragma unroll
        for (int ni = 0; ni < 4; ++ni) {
            const int r = wn * 64 + ni * 16 + l15;
            bf_[ni] = *(const bf16x8*)((const char*)Bs + r * 64 + l4 * 16);
        }
        __builtin_amdgcn_s_setprio(1);
#pragma unroll
        for (int mi = 0; mi < 4; ++mi)
#pragma unroll
            for (int ni = 0; ni < 4; ++ni)
                acc[mi][ni] = MFMA16(af[mi], bf_[ni], acc[mi][ni]);
        __builtin_amdgcn_s_setprio(0);
    }

#pragma unroll
    for (int mi = 0; mi < 4; ++mi) {
#pragma unroll
        for (int ni = 0; ni < 4; ++ni) {
            const int ng = n0 + wn * 64 + ni * 16 + l15;
            const int qkv = ng >> 10;       // uniform across 16-lane group
            const int nn = ng & 1023;
            const int hh = nn >> 6, dd = nn & 63;
            const int mg = m0 + wm * 64 + mi * 16 + l4 * 4;
            const int bb = mg >> 11, ss = mg & 2047;
            if (qkv == 2) {
                // V^T [BH][D][S]: 4 consecutive s at fixed d -> one 8B store
                const float bias = bv[nn];
                union { bf16 h[4]; short4v s4; } pk_;
#pragma unroll
                for (int j = 0; j < 4; ++j)
                    pk_.h[j] = (bf16)(acc[mi][ni][j] + bias);
                bf16* dst = Vo + ((size_t)(bb * NH + hh) * HD + dd) * SS + ss;
                *(short4v*)dst = pk_.s4;    // ss % 4 == 0 -> 8B aligned
            } else {
                const float* bp = (qkv == 0) ? bq : bk;
                bf16* op = (qkv == 0) ? Qo : Ko;
                const float bias = bp[nn];
                const float scl = (qkv == 0) ? 0.125f * LOG2E : 1.0f;
                bf16* dst = op + ((size_t)(bb * NH + hh) * SS + ss) * HD + dd;
#pragma unroll
                for (int j = 0; j < 4; ++j)
                    dst[(size_t)j * HD] = (bf16)((acc[mi][ni][j] + bias) * scl);
            }
        }
    }
}

// ---------- kernel 4: flash attention v14 — no split-K, direct out ----------
// R13 per-tile structure (best measured: both-groups-QK-first, mask C-init,
// static-shift softmax, permlane P-path, K and V^T both via global_load_lds
// with pre-swizzled sources, dbuf, 1 barrier/tile). 512 blocks x 2048 keys.
// Epilogue: in-kernel normalize + wave-private LDS bounce -> coalesced
// 128B-per-lane f32 out stores. No combine kernel, no partials.
__global__ __launch_bounds__(256) void attn_fwd(
    const bf16* __restrict__ Q, const bf16* __restrict__ K,
    const bf16* __restrict__ Vt_g, const float* __restrict__ mkl,
    float* __restrict__ out) {
    __shared__ __align__(16) char smem[32768];   // 4 x 8KB: Ks0 Ks1 Vt0 Vt1

    const int t = threadIdx.x, l = t & 63, w = t >> 6;
    const int l31 = l & 31, h = l >> 5;

    const int bid = blockIdx.x;
    const int nid = (bid & 7) * 64 + (bid >> 3);   // 512 = 8*64 bijective
    const int bh = nid >> 4, qb = nid & 15;
    const int b = bh >> 4, hh = bh & 15;
    const int q0 = qb * 128 + w * 32;

    const bf16* Qp  = Q + (size_t)bh * SS * HD;
    const bf16* Kp  = K + (size_t)bh * SS * HD;
    const bf16* Vpt = Vt_g + (size_t)bh * HD * SS;   // [D][S]
    const float* mkp = mkl + b * SS;

    // Q frags (B-operand): lane q = l31, d = c*16 + h*8 + e
    bf16x8 qf[4];
#pragma unroll
    for (int c = 0; c < 4; ++c)
        qf[c] = *(const bf16x8*)&Qp[(size_t)(q0 + l31) * HD + c * 16 + h * 8];

    float lrun = 0.f;
    f32x16 o0 = {}, o1 = {};   // O^T: rows d / d+32, col q = l31

    // ---- staging helpers (K and V^T via global_load_lds) ----
    auto stageK = [&](int tile, char* dst) {
        const int key0 = tile * 64;
#pragma unroll
        for (int cc = 0; cc < 2; ++cc) {
            const int c = t + cc * 256;
            const int row = c >> 3;                  // key
            const int csw = (c & 7) ^ ((row ^ (row >> 3)) & 7);
            gload16(&Kp[(size_t)(key0 + row) * HD + csw * 8], dst + c * 16);
        }
    };
    auto stageVt = [&](int tile, char* dst) {
        const int key0 = tile * 64;
#pragma unroll
        for (int cc = 0; cc < 2; ++cc) {
            const int c = t + cc * 256;
            const int row = c >> 3;                  // d
            const int csw = (c & 7) ^ ((row ^ (row >> 3)) & 7);
            gload16(&Vpt[(size_t)row * SS + key0 + csw * 8], dst + c * 16);
        }
    };

    // ---- prologue: stage tile 0 ----
    stageK(0, smem);
    stageVt(0, smem + 16384);
    __syncthreads();

    constexpr int NT = SS / 64;   // 32
#pragma unroll 1
    for (int kt = 0; kt < NT; ++kt) {
        char* Ks  = smem + (kt & 1) * 8192;
        char* Vt  = smem + 16384 + (kt & 1) * 8192;
        char* Ksn = smem + ((kt + 1) & 1) * 8192;
        char* Vtn = smem + 16384 + ((kt + 1) & 1) * 8192;
        const int key0 = kt * 64;
        const bool more = (kt + 1) < NT;

        // ---- early-issue next tile staging (async DMA, other buffers) ----
        if (more) {
            stageK(kt + 1, Ksn);
            stageVt(kt + 1, Vtn);
        }

        // ---- QK^T both groups; C-operand = mask' (log2-domain additive) ----
        f32x16 s0, s1;
#pragma unroll
        for (int rq = 0; rq < 4; ++rq) {
            const f32x4 m0v = *(const f32x4*)&mkp[key0 + rq * 8 + 4 * h];
            const f32x4 m1v = *(const f32x4*)&mkp[key0 + 32 + rq * 8 + 4 * h];
#pragma unroll
            for (int j = 0; j < 4; ++j) {
                s0[rq * 4 + j] = m0v[j];
                s1[rq * 4 + j] = m1v[j];
            }
        }
        __builtin_amdgcn_s_setprio(1);
#pragma unroll
        for (int c = 0; c < 4; ++c) {
            const int r0 = l31;
            bf16x8 kf0 = *(const bf16x8*)(Ks + r0 * 128 +
                                          ((c * 32 + h * 16) ^ SW(r0)));
            s0 = MFMA32(kf0, qf[c], s0);
        }
#pragma unroll
        for (int c = 0; c < 4; ++c) {
            const int r1 = 32 + l31;
            bf16x8 kf1 = *(const bf16x8*)(Ks + r1 * 128 +
                                          ((c * 32 + h * 16) ^ SW(r1)));
            s1 = MFMA32(kf1, qf[c], s1);
        }
        __builtin_amdgcn_s_setprio(0);

        // ---- softmax + PV per group (static shift; p = 2^s) ----
#pragma unroll
        for (int g = 0; g < 2; ++g) {
            f32x16& st = g ? s1 : s0;
            float ps = 0.f;
#pragma unroll
            for (int r = 0; r < 16; ++r) {
                const float p = exp2i(st[r]);
                st[r] = p;
                ps += p;
            }
            lrun += ps;
#pragma unroll
            for (int cc = 0; cc < 2; ++cc) {
                uint32_t wA = pack_bf16(st[8 * cc + 0], st[8 * cc + 1]);
                uint32_t wB = pack_bf16(st[8 * cc + 2], st[8 * cc + 3]);
                uint32_t wC = pack_bf16(st[8 * cc + 4], st[8 * cc + 5]);
                uint32_t wD = pack_bf16(st[8 * cc + 6], st[8 * cc + 7]);
                plswap(wA, wC);
                plswap(wB, wD);
                union { uint32_t u[4]; bf16x8 v; } pb;
                pb.u[0] = wA; pb.u[1] = wB; pb.u[2] = wC; pb.u[3] = wD;
                const int colb = g * 64 + cc * 32 + h * 16;
                __builtin_amdgcn_s_setprio(1);
                {
                    bf16x8 vf0 = *(const bf16x8*)(Vt + l31 * 128 +
                                                  (colb ^ SW(l31)));
                    o0 = MFMA32(vf0, pb.v, o0);
                    const int r1 = 32 + l31;
                    bf16x8 vf1 = *(const bf16x8*)(Vt + r1 * 128 +
                                                  (colb ^ SW(r1)));
                    o1 = MFMA32(vf1, pb.v, o1);
                }
                __builtin_amdgcn_s_setprio(0);
            }
        }
        __syncthreads();   // single barrier per tile (drains next-tile DMA)
    }

    // ---- epilogue: normalize, wave-private LDS bounce, coalesced store ----
    lrun += __shfl_xor(lrun, 32);
    const float inv = 1.0f / lrun;
    char* myB = smem + w * 8192;   // [32 q][16 slots x 16B], slot ^= (q&15)
#pragma unroll
    for (int r4 = 0; r4 < 4; ++r4) {
        f32x4 a, b2;
#pragma unroll
        for (int j = 0; j < 4; ++j) {
            a[j]  = o0[r4 * 4 + j] * inv;
            b2[j] = o1[r4 * 4 + j] * inv;
        }
        // d = r4*8 + 4h (+32 for o1) -> slot = d>>2
        const int s0_ = 2 * r4 + h;
        const int s1_ = 8 + 2 * r4 + h;
        *(f32x4*)(myB + l31 * 256 + ((s0_ ^ (l31 & 15)) * 16)) = a;
        *(f32x4*)(myB + l31 * 256 + ((s1_ ^ (l31 & 15)) * 16)) = b2;
    }
    // wave-private: per-wave DS ordering makes the read-back safe (no barrier)
    const int qr = l >> 1, halfd = l & 1;
    float* op = &out[((size_t)(b * SS) + q0 + qr) * HID + hh * HD + halfd * 32];
#pragma unroll
    for (int s = 0; s < 8; ++s) {
        const int slot = halfd * 8 + s;
        f32x4 v = *(const f32x4*)(myB + qr * 256 + ((slot ^ (qr & 15)) * 16));
        *(f32x4*)(op + s * 4) = v;
    }
}

// ---------- launch ----------
extern "C" void kernel_launch(void* const* d_in, const int* in_sizes, int n_in,
                              void* d_out, int out_size, void* d_ws, size_t ws_size,
                              hipStream_t stream) {
    (void)in_sizes; (void)n_in; (void)out_size; (void)ws_size;
    const float* hs  = (const float*)d_in[0];
    const float* msk = (const float*)d_in[1];
    const float* Wq  = (const float*)d_in[2];
    const float* bq  = (const float*)d_in[3];
    const float* Wk  = (const float*)d_in[4];
    const float* bk  = (const float*)d_in[5];
    const float* Wv  = (const float*)d_in[6];
    const float* bv  = (const float*)d_in[7];
    float* out = (float*)d_out;
    char* ws = (char*)d_ws;
    const size_t MB = 1 << 20;

    bf16* Qb  = (bf16*)ws;                    // 0..8MB   [B,H,S,D]
    bf16* Kb  = (bf16*)(ws + 8 * MB);         // 8..16    [B,H,S,D]
    bf16* Vb  = (bf16*)(ws + 16 * MB);        // 16..24   [BH][D][S] (transposed)
    float* mk2 = (float*)(ws + 24 * MB);      // 24MB + 16KB
    bf16* Xb  = (bf16*)(ws + 25 * MB);        // 25..33
    bf16* Wt  = (bf16*)(ws + 33 * MB);        // 33..39

    cvt_hidden<<<dim3(MROW * HID / (256 * 8)), dim3(256), 0, stream>>>(hs, Xb);
    maskcvt<<<dim3(BB * SS / 256), dim3(256), 0, stream>>>(msk, mk2);
    wtrans<<<dim3(32, 32, 3), dim3(32, 8), 0, stream>>>(Wq, Wk, Wv, Wt);
    qkv_gemm<<<dim3(768), dim3(256), 0, stream>>>(
        Xb, Wt, bq, bk, bv, Qb, Kb, Vb);
    attn_fwd<<<dim3(512), dim3(256), 0, stream>>>(Qb, Kb, Vb, mk2, out);
}

// Round 15
// 110.736 us; speedup vs baseline: 1.1058x; 1.0356x over previous
//
#include <hip/hip_runtime.h>
#include <cstdint>
#include <cstddef>

// ---------- types ----------
typedef __bf16 bf16;
typedef __attribute__((ext_vector_type(8))) __bf16 bf16x8;
typedef __attribute__((ext_vector_type(4))) float f32x4;
typedef __attribute__((ext_vector_type(16))) float f32x16;
typedef __attribute__((ext_vector_type(4))) short short4v;

#define MFMA16(a, b, c) __builtin_amdgcn_mfma_f32_16x16x32_bf16((a), (b), (c), 0, 0, 0)
#define MFMA32(a, b, c) __builtin_amdgcn_mfma_f32_32x32x16_bf16((a), (b), (c), 0, 0, 0)

// Problem constants (B=2, S=2048, HIDDEN=1024, H=16, D=64)
static constexpr int BB   = 2;
static constexpr int SS   = 2048;
static constexpr int HID  = 1024;
static constexpr int NH   = 16;
static constexpr int HD   = 64;
static constexpr int MROW = BB * SS;     // 4096
static constexpr int NQKV = 3 * HID;     // 3072
static constexpr float LOG2E = 1.4426950408889634f;
static constexpr float MSHIFT = 16.0f;   // static softmax shift (log2 domain)

// XOR swizzle on 16B slots
__device__ __forceinline__ int SW(int r) { return ((r ^ (r >> 3)) & 7) << 4; }

__device__ __forceinline__ uint32_t pack_bf16(float a, float b) {
    union { bf16 h[2]; uint32_t u; } x;
    x.h[0] = (bf16)a; x.h[1] = (bf16)b;
    return x.u;
}

__device__ __forceinline__ float exp2i(float x) {
    float r; asm("v_exp_f32 %0, %1" : "=v"(r) : "v"(x)); return r;
}

// v_permlane32_swap_b32: a' = [a.lo | b.lo], b' = [a.hi | b.hi]
__device__ __forceinline__ void plswap(uint32_t& a, uint32_t& b) {
    asm("v_permlane32_swap_b32 %0, %1" : "+v"(a), "+v"(b));
}

// async global->LDS, 16B per lane
__device__ __forceinline__ void gload16(const void* g, void* l) {
    __builtin_amdgcn_global_load_lds(
        (const __attribute__((address_space(1))) void*)g,
        (__attribute__((address_space(3))) void*)l, 16, 0, 0);
}

// ---------- kernel 1: fp32 -> bf16 convert (+ fused mask precompute) ----------
__global__ __launch_bounds__(256) void cvt_hidden(const float* __restrict__ in,
                                                  bf16* __restrict__ out,
                                                  const float* __restrict__ msk,
                                                  float* __restrict__ mk2) {
    const int blk = blockIdx.x;
    if (blk >= 2048) {                       // 16 tail blocks: mask * log2e - 16
        const int i = (blk - 2048) * 256 + threadIdx.x;   // 0..4095
        mk2[i] = msk[i] * LOG2E - MSHIFT;
        return;
    }
    const int i = (blk * 256 + threadIdx.x) * 8;
    float4 f0 = *(const float4*)&in[i];
    float4 f1 = *(const float4*)&in[i + 4];
    bf16x8 o;
    o[0] = (bf16)f0.x; o[1] = (bf16)f0.y; o[2] = (bf16)f0.z; o[3] = (bf16)f0.w;
    o[4] = (bf16)f1.x; o[5] = (bf16)f1.y; o[6] = (bf16)f1.z; o[7] = (bf16)f1.w;
    *(bf16x8*)&out[i] = o;
}

// ---------- kernel 2: transpose-convert W -> Wt [n][k] bf16 ----------
__global__ __launch_bounds__(256) void wtrans(const float* __restrict__ Wq,
                                              const float* __restrict__ Wk,
                                              const float* __restrict__ Wv,
                                              bf16* __restrict__ Wt) {
    __shared__ float tile[32][33];
    const float* W = (blockIdx.z == 0) ? Wq : (blockIdx.z == 1) ? Wk : Wv;
    bf16* O = Wt + (size_t)blockIdx.z * HID * HID;
    const int x  = blockIdx.x * 32 + threadIdx.x;
    const int y0 = blockIdx.y * 32;
#pragma unroll
    for (int i = threadIdx.y; i < 32; i += 8)
        tile[i][threadIdx.x] = W[(size_t)(y0 + i) * HID + x];
    __syncthreads();
    const int k = y0 + threadIdx.x;
#pragma unroll
    for (int i = threadIdx.y; i < 32; i += 8)
        O[(size_t)(blockIdx.x * 32 + i) * HID + k] = (bf16)tile[threadIdx.x][i];
}

// ---------- kernel 3: QKV GEMM (XCD remap + 1-barrier dbuf pipeline) ----------
// Q,K written [B,H,S,D]; V written PRE-TRANSPOSED [B*H][D][S].
// Pipeline = attn's proven schedule: prologue stage; loop { stage next ->
// other buffer (async DMA); ds_read current; MFMA; barrier }. One barrier
// per K-step; the syncthreads vmcnt-drain publishes the next buffer.
__global__ __launch_bounds__(256) void qkv_gemm(
    const bf16* __restrict__ A, const bf16* __restrict__ Bt,
    const float* __restrict__ bq, const float* __restrict__ bk,
    const float* __restrict__ bv,
    bf16* __restrict__ Qo, bf16* __restrict__ Ko, bf16* __restrict__ Vo) {
    __shared__ __align__(16) bf16 As0[128 * 32];
    __shared__ __align__(16) bf16 As1[128 * 32];
    __shared__ __align__(16) bf16 Bs0[128 * 32];
    __shared__ __align__(16) bf16 Bs1[128 * 32];
    const int t = threadIdx.x, l = t & 63;
    const int l15 = l & 15, l4 = l >> 4;
    const int w = t >> 6;
    const int wm = w >> 1, wn = w & 1;

    const int bid = blockIdx.x;
    const int nid = (bid & 7) * 96 + (bid >> 3);   // bijective: 768 = 8*96
    const int m0 = (nid & 31) * 128;
    const int n0 = (nid >> 5) * 128;

    f32x4 acc[4][4] = {};

    auto stage = [&](int kt, bf16* Asd, bf16* Bsd) {
        const int k0 = kt * 32;
#pragma unroll
        for (int cc = 0; cc < 2; ++cc) {
            const int c = t + cc * 256;
            const int row = c >> 2, col = (c & 3) * 8;
            gload16(&A[(size_t)(m0 + row) * HID + k0 + col], (char*)Asd + c * 16);
            gload16(&Bt[(size_t)(n0 + row) * HID + k0 + col], (char*)Bsd + c * 16);
        }
    };

    stage(0, As0, Bs0);
    __syncthreads();

#pragma unroll 1
    for (int kt = 0; kt < 32; ++kt) {
        bf16* As = (kt & 1) ? As1 : As0;
        bf16* Bs = (kt & 1) ? Bs1 : Bs0;
        if (kt < 31) stage(kt + 1, (kt & 1) ? As0 : As1, (kt & 1) ? Bs0 : Bs1);

        bf16x8 af[4], bf_[4];
#pragma unroll
        for (int mi = 0; mi < 4; ++mi) {
            const int r = wm * 64 + mi * 16 + l15;
            af[mi] = *(const bf16x8*)((const char*)As + r * 64 + l4 * 16);
        }
#pragma unroll
        for (int ni = 0; ni < 4; ++ni) {
            const int r = wn * 64 + ni * 16 + l15;
            bf_[ni] = *(const bf16x8*)((const char*)Bs + r * 64 + l4 * 16);
        }
        __builtin_amdgcn_s_setprio(1);
#pragma unroll
        for (int mi = 0; mi < 4; ++mi)
#pragma unroll
            for (int ni = 0; ni < 4; ++ni)
                acc[mi][ni] = MFMA16(af[mi], bf_[ni], acc[mi][ni]);
        __builtin_amdgcn_s_setprio(0);
        __syncthreads();   // single barrier: drains next-tile DMA, fences reads
    }

#pragma unroll
    for (int mi = 0; mi < 4; ++mi) {
#pragma unroll
        for (int ni = 0; ni < 4; ++ni) {
            const int ng = n0 + wn * 64 + ni * 16 + l15;
            const int qkv = ng >> 10;       // uniform across 16-lane group
            const int nn = ng & 1023;
            const int hh = nn >> 6, dd = nn & 63;
            const int mg = m0 + wm * 64 + mi * 16 + l4 * 4;
            const int bb = mg >> 11, ss = mg & 2047;
            if (qkv == 2) {
                // V^T [BH][D][S]: 4 consecutive s at fixed d -> one 8B store
                const float bias = bv[nn];
                union { bf16 h[4]; short4v s4; } pk_;
#pragma unroll
                for (int j = 0; j < 4; ++j)
                    pk_.h[j] = (bf16)(acc[mi][ni][j] + bias);
                bf16* dst = Vo + ((size_t)(bb * NH + hh) * HD + dd) * SS + ss;
                *(short4v*)dst = pk_.s4;    // ss % 4 == 0 -> 8B aligned
            } else {
                const float* bp = (qkv == 0) ? bq : bk;
                bf16* op = (qkv == 0) ? Qo : Ko;
                const float bias = bp[nn];
                const float scl = (qkv == 0) ? 0.125f * LOG2E : 1.0f;
                bf16* dst = op + ((size_t)(bb * NH + hh) * SS + ss) * HD + dd;
#pragma unroll
                for (int j = 0; j < 4; ++j)
                    dst[(size_t)j * HD] = (bf16)((acc[mi][ni][j] + bias) * scl);
            }
        }
    }
}

// ---------- kernel 4: flash attention v15 ----------
// Identical to R14 except the four LDS buffers are DISTINCT __shared__
// objects (R13 style) — isolating the merged-smem variable that is the
// remaining candidate for R14's attn regression (71.6 vs R13's 67.3-class).
__global__ __launch_bounds__(256) void attn_fwd(
    const bf16* __restrict__ Q, const bf16* __restrict__ K,
    const bf16* __restrict__ Vt_g, const float* __restrict__ mkl,
    float* __restrict__ out) {
    __shared__ __align__(16) char Ks0[64 * 128];
    __shared__ __align__(16) char Ks1[64 * 128];
    __shared__ __align__(16) char Vt0[64 * 128];
    __shared__ __align__(16) char Vt1[64 * 128];

    const int t = threadIdx.x, l = t & 63, w = t >> 6;
    const int l31 = l & 31, h = l >> 5;

    const int bid = blockIdx.x;
    const int nid = (bid & 7) * 64 + (bid >> 3);   // 512 = 8*64 bijective
    const int bh = nid >> 4, qb = nid & 15;
    const int b = bh >> 4, hh = bh & 15;
    const int q0 = qb * 128 + w * 32;

    const bf16* Qp  = Q + (size_t)bh * SS * HD;
    const bf16* Kp  = K + (size_t)bh * SS * HD;
    const bf16* Vpt = Vt_g + (size_t)bh * HD * SS;   // [D][S]
    const float* mkp = mkl + b * SS;

    // Q frags (B-operand): lane q = l31, d = c*16 + h*8 + e
    bf16x8 qf[4];
#pragma unroll
    for (int c = 0; c < 4; ++c)
        qf[c] = *(const bf16x8*)&Qp[(size_t)(q0 + l31) * HD + c * 16 + h * 8];

    float lrun = 0.f;
    f32x16 o0 = {}, o1 = {};   // O^T: rows d / d+32, col q = l31

    // ---- staging helpers (K and V^T via global_load_lds) ----
    auto stageK = [&](int tile, char* dst) {
        const int key0 = tile * 64;
#pragma unroll
        for (int cc = 0; cc < 2; ++cc) {
            const int c = t + cc * 256;
            const int row = c >> 3;                  // key
            const int csw = (c & 7) ^ ((row ^ (row >> 3)) & 7);
            gload16(&Kp[(size_t)(key0 + row) * HD + csw * 8], dst + c * 16);
        }
    };
    auto stageVt = [&](int tile, char* dst) {
        const int key0 = tile * 64;
#pragma unroll
        for (int cc = 0; cc < 2; ++cc) {
            const int c = t + cc * 256;
            const int row = c >> 3;                  // d
            const int csw = (c & 7) ^ ((row ^ (row >> 3)) & 7);
            gload16(&Vpt[(size_t)row * SS + key0 + csw * 8], dst + c * 16);
        }
    };

    // ---- prologue: stage tile 0 ----
    stageK(0, Ks0);
    stageVt(0, Vt0);
    __syncthreads();

    constexpr int NT = SS / 64;   // 32
#pragma unroll 1
    for (int kt = 0; kt < NT; ++kt) {
        char* Ks  = (kt & 1) ? Ks1 : Ks0;
        char* Vt  = (kt & 1) ? Vt1 : Vt0;
        char* Ksn = (kt & 1) ? Ks0 : Ks1;
        char* Vtn = (kt & 1) ? Vt0 : Vt1;
        const int key0 = kt * 64;
        const bool more = (kt + 1) < NT;

        // ---- early-issue next tile staging (async DMA, other buffers) ----
        if (more) {
            stageK(kt + 1, Ksn);
            stageVt(kt + 1, Vtn);
        }

        // ---- QK^T both groups; C-operand = mask' (log2-domain additive) ----
        f32x16 s0, s1;
#pragma unroll
        for (int rq = 0; rq < 4; ++rq) {
            const f32x4 m0v = *(const f32x4*)&mkp[key0 + rq * 8 + 4 * h];
            const f32x4 m1v = *(const f32x4*)&mkp[key0 + 32 + rq * 8 + 4 * h];
#pragma unroll
            for (int j = 0; j < 4; ++j) {
                s0[rq * 4 + j] = m0v[j];
                s1[rq * 4 + j] = m1v[j];
            }
        }
        __builtin_amdgcn_s_setprio(1);
#pragma unroll
        for (int c = 0; c < 4; ++c) {
            const int r0 = l31;
            bf16x8 kf0 = *(const bf16x8*)(Ks + r0 * 128 +
                                          ((c * 32 + h * 16) ^ SW(r0)));
            s0 = MFMA32(kf0, qf[c], s0);
        }
#pragma unroll
        for (int c = 0; c < 4; ++c) {
            const int r1 = 32 + l31;
            bf16x8 kf1 = *(const bf16x8*)(Ks + r1 * 128 +
                                          ((c * 32 + h * 16) ^ SW(r1)));
            s1 = MFMA32(kf1, qf[c], s1);
        }
        __builtin_amdgcn_s_setprio(0);

        // ---- softmax + PV per group (static shift; p = 2^s) ----
#pragma unroll
        for (int g = 0; g < 2; ++g) {
            f32x16& st = g ? s1 : s0;
            float ps = 0.f;
#pragma unroll
            for (int r = 0; r < 16; ++r) {
                const float p = exp2i(st[r]);
                st[r] = p;
                ps += p;
            }
            lrun += ps;
#pragma unroll
            for (int cc = 0; cc < 2; ++cc) {
                uint32_t wA = pack_bf16(st[8 * cc + 0], st[8 * cc + 1]);
                uint32_t wB = pack_bf16(st[8 * cc + 2], st[8 * cc + 3]);
                uint32_t wC = pack_bf16(st[8 * cc + 4], st[8 * cc + 5]);
                uint32_t wD = pack_bf16(st[8 * cc + 6], st[8 * cc + 7]);
                plswap(wA, wC);
                plswap(wB, wD);
                union { uint32_t u[4]; bf16x8 v; } pb;
                pb.u[0] = wA; pb.u[1] = wB; pb.u[2] = wC; pb.u[3] = wD;
                const int colb = g * 64 + cc * 32 + h * 16;
                __builtin_amdgcn_s_setprio(1);
                {
                    bf16x8 vf0 = *(const bf16x8*)(Vt + l31 * 128 +
                                                  (colb ^ SW(l31)));
                    o0 = MFMA32(vf0, pb.v, o0);
                    const int r1 = 32 + l31;
                    bf16x8 vf1 = *(const bf16x8*)(Vt + r1 * 128 +
                                                  (colb ^ SW(r1)));
                    o1 = MFMA32(vf1, pb.v, o1);
                }
                __builtin_amdgcn_s_setprio(0);
            }
        }
        __syncthreads();   // single barrier per tile (drains next-tile DMA)
    }

    // ---- epilogue: normalize, wave-private LDS bounce, coalesced store ----
    lrun += __shfl_xor(lrun, 32);
    const float inv = 1.0f / lrun;
    char* myB = (w == 0) ? Ks0 : (w == 1) ? Ks1 : (w == 2) ? Vt0 : Vt1;
#pragma unroll
    for (int r4 = 0; r4 < 4; ++r4) {
        f32x4 a, b2;
#pragma unroll
        for (int j = 0; j < 4; ++j) {
            a[j]  = o0[r4 * 4 + j] * inv;
            b2[j] = o1[r4 * 4 + j] * inv;
        }
        // d = r4*8 + 4h (+32 for o1) -> slot = d>>2
        const int s0_ = 2 * r4 + h;
        const int s1_ = 8 + 2 * r4 + h;
        *(f32x4*)(myB + l31 * 256 + ((s0_ ^ (l31 & 15)) * 16)) = a;
        *(f32x4*)(myB + l31 * 256 + ((s1_ ^ (l31 & 15)) * 16)) = b2;
    }
    // wave-private: per-wave DS ordering makes the read-back safe (no barrier)
    const int qr = l >> 1, halfd = l & 1;
    float* op = &out[((size_t)(b * SS) + q0 + qr) * HID + hh * HD + halfd * 32];
#pragma unroll
    for (int s = 0; s < 8; ++s) {
        const int slot = halfd * 8 + s;
        f32x4 v = *(const f32x4*)(myB + qr * 256 + ((slot ^ (qr & 15)) * 16));
        *(f32x4*)(op + s * 4) = v;
    }
}

// ---------- launch ----------
extern "C" void kernel_launch(void* const* d_in, const int* in_sizes, int n_in,
                              void* d_out, int out_size, void* d_ws, size_t ws_size,
                              hipStream_t stream) {
    (void)in_sizes; (void)n_in; (void)out_size; (void)ws_size;
    const float* hs  = (const float*)d_in[0];
    const float* msk = (const float*)d_in[1];
    const float* Wq  = (const float*)d_in[2];
    const float* bq  = (const float*)d_in[3];
    const float* Wk  = (const float*)d_in[4];
    const float* bk  = (const float*)d_in[5];
    const float* Wv  = (const float*)d_in[6];
    const float* bv  = (const float*)d_in[7];
    float* out = (float*)d_out;
    char* ws = (char*)d_ws;
    const size_t MB = 1 << 20;

    bf16* Qb  = (bf16*)ws;                    // 0..8MB   [B,H,S,D]
    bf16* Kb  = (bf16*)(ws + 8 * MB);         // 8..16    [B,H,S,D]
    bf16* Vb  = (bf16*)(ws + 16 * MB);        // 16..24   [BH][D][S] (transposed)
    float* mk2 = (float*)(ws + 24 * MB);      // 24MB + 16KB
    bf16* Xb  = (bf16*)(ws + 25 * MB);        // 25..33
    bf16* Wt  = (bf16*)(ws + 33 * MB);        // 33..39

    cvt_hidden<<<dim3(2048 + 16), dim3(256), 0, stream>>>(hs, Xb, msk, mk2);
    wtrans<<<dim3(32, 32, 3), dim3(32, 8), 0, stream>>>(Wq, Wk, Wv, Wt);
    qkv_gemm<<<dim3(768), dim3(256), 0, stream>>>(
        Xb, Wt, bq, bk, bv, Qb, Kb, Vb);
    attn_fwd<<<dim3(512), dim3(256), 0, stream>>>(Qb, Kb, Vb, mk2, out);
}